// Round 3
// baseline (1552.448 us; speedup 1.0000x reference)
//
#include <hip/hip_runtime.h>
#include <hip/hip_fp16.h>
#include <math.h>

#define NT      512
#define NPIX    16384
#define NSLICES 8
#define NMODES  4
#define OBJW    512
#define LSTR    136        // padded major stride (half2 units): 136%32=8

typedef float v2f __attribute__((ext_vector_type(2)));

// ---- packed fp32 complex primitives (VOP3P) --------------------------------
__device__ __forceinline__ v2f pk_add(v2f a, v2f b) {
    v2f d; asm("v_pk_add_f32 %0, %1, %2" : "=v"(d) : "v"(a), "v"(b)); return d;
}
__device__ __forceinline__ v2f pk_sub(v2f a, v2f b) {
    v2f d; asm("v_pk_add_f32 %0, %1, %2 neg_lo:[0,1] neg_hi:[0,1]"
               : "=v"(d) : "v"(a), "v"(b)); return d;
}
__device__ __forceinline__ v2f pk_fma(v2f a, v2f b, v2f c) {
    v2f d; asm("v_pk_fma_f32 %0, %1, %2, %3" : "=v"(d) : "v"(a), "v"(b), "v"(c)); return d;
}
// d = a*b (complex):  t=(ax*bx, ay*bx);  d=(t.x - ay*by, t.y + ax*by)
__device__ __forceinline__ v2f pk_cmul(v2f a, v2f b) {
    v2f t, d;
    asm("v_pk_mul_f32 %0, %1, %2 op_sel:[0,0] op_sel_hi:[1,0]"
        : "=v"(t) : "v"(a), "v"(b));
    asm("v_pk_fma_f32 %0, %1, %2, %3 op_sel:[1,1,0] op_sel_hi:[0,1,1] neg_lo:[1,0,0]"
        : "=v"(d) : "v"(a), "v"(b), "v"(t));
    return d;
}
// d = a*conj(b)
__device__ __forceinline__ v2f pk_cmulc(v2f a, v2f b) {
    v2f t, d;
    asm("v_pk_mul_f32 %0, %1, %2 op_sel:[0,0] op_sel_hi:[1,0]"
        : "=v"(t) : "v"(a), "v"(b));
    asm("v_pk_fma_f32 %0, %1, %2, %3 op_sel:[1,1,0] op_sel_hi:[0,1,1] neg_hi:[1,0,0]"
        : "=v"(d) : "v"(a), "v"(b), "v"(t));
    return d;
}
__device__ __forceinline__ v2f pk_mnegi(v2f a) { return (v2f){a.y, -a.x}; }  // a * -i
__device__ __forceinline__ v2f pk_mposi(v2f a) { return (v2f){-a.y, a.x}; }  // a * +i

// 4-bit reversal (constexpr -> folds to literals in unrolled loops)
__host__ __device__ constexpr int BR4(int p) {
    return ((p & 1) << 3) | ((p & 2) << 1) | ((p & 4) >> 1) | ((p & 8) >> 3);
}
__host__ __device__ constexpr int BR3(int c) {
    return ((c & 1) << 2) | (c & 2) | ((c & 4) >> 2);
}

// ---- lane exchange primitives ---------------------------------------------
__device__ __forceinline__ float xor1f(float x) {
    int i = __float_as_int(x);
    return __int_as_float(__builtin_amdgcn_update_dpp(i, i, 0xB1, 0xF, 0xF, false));
}
__device__ __forceinline__ float xor2f(float x) {
    int i = __float_as_int(x);
    return __int_as_float(__builtin_amdgcn_update_dpp(i, i, 0x4E, 0xF, 0xF, false));
}
__device__ __forceinline__ float xor4f(float x) {
    return __int_as_float(__builtin_amdgcn_ds_swizzle(__float_as_int(x), 0x101F));
}

// cross-8 stage-A twiddle fA(c) = (c<4) ? 1 : W8^(c-4)
__device__ __constant__ float FA_RE[8] = {1,1,1,1, 1.0f,  0.707106781f,  0.0f, -0.707106781f};
__device__ __constant__ float FA_IM[8] = {0,0,0,0, 0.0f, -0.707106781f, -1.0f, -0.707106781f};

// ---- local 16-point FFT in registers (packed) ------------------------------
__device__ __forceinline__ void fft16_fwd(v2f v[16], const v2f* W) {
    #pragma unroll
    for (int s = 8; s >= 1; s >>= 1) {
        #pragma unroll
        for (int q = 0; q < 16; q += 2 * s) {
            #pragma unroll
            for (int j = 0; j < s; j++) {
                const int tw = j * (8 / s);
                v2f u = v[q + j], w = v[q + j + s];
                v[q + j] = pk_add(u, w);
                v2f d = pk_sub(u, w);
                v[q + j + s] = (tw == 0) ? d
                             : (tw == 4) ? pk_mnegi(d)
                                         : pk_cmulc(d, W[tw]);
            }
        }
    }
}
__device__ __forceinline__ void fft16_inv(v2f v[16], const v2f* W) {
    #pragma unroll
    for (int s = 1; s <= 8; s <<= 1) {
        #pragma unroll
        for (int q = 0; q < 16; q += 2 * s) {
            #pragma unroll
            for (int j = 0; j < s; j++) {
                const int tw = j * (8 / s);
                v2f u = v[q + j], w = v[q + j + s];
                v2f tv = (tw == 0) ? w
                       : (tw == 4) ? pk_mposi(w)
                                   : pk_cmul(w, W[tw]);
                v[q + j]     = pk_add(u, tv);
                v[q + j + s] = pk_sub(u, tv);
            }
        }
    }
}

// ---- cross-thread DFT8 over sub-index c (xor 4,2,1) ------------------------
__device__ __forceinline__ void cross8_fwd(v2f v[16], v2f sAp, v2f sBp, v2f sCp,
                                           v2f fA, v2f rrf) {
    #pragma unroll
    for (int p = 0; p < 16; p++) {
        v2f o;
        o.x = xor4f(v[p].x); o.y = xor4f(v[p].y);
        v2f a = pk_fma(sAp, v[p], o);
        v2f b = pk_cmul(a, fA);
        o.x = xor2f(b.x); o.y = xor2f(b.y);
        v2f n = pk_fma(sBp, b, o);
        v2f r = pk_cmul(n, rrf);
        o.x = xor1f(r.x); o.y = xor1f(r.y);
        v[p] = pk_fma(sCp, r, o);
    }
}
__device__ __forceinline__ void cross8_inv(v2f v[16], v2f sAp, v2f sBp, v2f sCp,
                                           v2f fA, v2f rrf) {
    #pragma unroll
    for (int p = 0; p < 16; p++) {
        v2f o;
        o.x = xor1f(v[p].x); o.y = xor1f(v[p].y);
        v2f n = pk_fma(sCp, v[p], o);
        v2f r = pk_cmulc(n, rrf);
        o.x = xor2f(r.x); o.y = xor2f(r.y);
        v2f b = pk_fma(sBp, r, o);
        v2f a = pk_cmulc(b, fA);
        o.x = xor4f(a.x); o.y = xor4f(a.y);
        v[p] = pk_fma(sAp, a, o);
    }
}

// ---- pass A (local-first): input reg i = elem c+8i; out reg p = BR4(p)+16rc
__device__ __forceinline__ void pass_A_fwd(v2f v[16], int c, v2f sAp, v2f sBp,
                                           v2f sCp, v2f fA, v2f rrf,
                                           const v2f* W, const v2f* tA) {
    fft16_fwd(v, W);
    #pragma unroll
    for (int p = 0; p < 16; p++) v[p] = pk_cmul(v[p], tA[8 * p + c]);
    cross8_fwd(v, sAp, sBp, sCp, fA, rrf);
}
__device__ __forceinline__ void pass_A_inv(v2f v[16], int c, v2f sAp, v2f sBp,
                                           v2f sCp, v2f fA, v2f rrf,
                                           const v2f* W, const v2f* tA) {
    cross8_inv(v, sAp, sBp, sCp, fA, rrf);
    #pragma unroll
    for (int p = 0; p < 16; p++) v[p] = pk_cmulc(v[p], tA[8 * p + c]);
    fft16_inv(v, W);
}

// ---- pass B (cross-first): input reg i = elem i+16c
__device__ __forceinline__ void pass_B_fwd(v2f v[16], int c, v2f sAp, v2f sBp,
                                           v2f sCp, v2f fA, v2f rrf,
                                           const v2f* W, const v2f* tB) {
    cross8_fwd(v, sAp, sBp, sCp, fA, rrf);
    #pragma unroll
    for (int i = 0; i < 16; i++) v[i] = pk_cmul(v[i], tB[8 * i + c]);
    fft16_fwd(v, W);
}
__device__ __forceinline__ void pass_B_inv(v2f v[16], int c, v2f sAp, v2f sBp,
                                           v2f sCp, v2f fA, v2f rrf,
                                           const v2f* W, const v2f* tB) {
    fft16_inv(v, W);
    #pragma unroll
    for (int i = 0; i < 16; i++) v[i] = pk_cmulc(v[i], tB[8 * i + c]);
    cross8_inv(v, sAp, sBp, sCp, fA, rrf);
}

// ---- conversions -----------------------------------------------------------
__device__ __forceinline__ __half2 toh2(v2f a) {
    return __float22half2_rn(make_float2(a.x, a.y));
}
__device__ __forceinline__ v2f frh2(__half2 h) {
    float2 f = __half22float2(h);
    return (v2f){f.x, f.y};
}

// ---- main kernel: 512 threads, 2 rows/thread (g0 and g0+64) ----------------
// 2 WGs/CU (2x75.8KB LDS = 151.5KB): two independent barrier domains per CU
// fill each other's transpose/barrier bubbles. __launch_bounds__(512,4) caps
// VGPR at 128 so both WGs are schedulable.
__global__ void
__launch_bounds__(512, 4)
multislice_kernel(const float* __restrict__ probe_re,
                  const float* __restrict__ probe_im,
                  const float* __restrict__ obj_re,
                  const float* __restrict__ obj_im,
                  const int*   __restrict__ positions,
                  float*       __restrict__ out)
{
    __shared__ __half2 LTH[128 * LSTR];   // 69632 B transpose buffer (fp16)
    __shared__ v2f     tA[128];           // pass-A twiddle [8p+c]
    __shared__ v2f     tB[128];           // pass-B twiddle [8i+c]
    __shared__ v2f     pytp[128];         // prop y-factor/16384, kh=br3(c)+8BR4(p)

    const int t  = threadIdx.x;
    const int g0 = t >> 3;                      // 0..63
    const int c  = t & 7;
    const int rc = BR3(c);
    const int ga = g0, gb = g0 + 64;            // this thread's two rows
    const int gha = ga >> 4, ghb = gb >> 4;
    const int rho_a = ((ga & 15) << 3) | gha;
    const int rho_b = ((gb & 15) << 3) | ghb;
    const int n  = blockIdx.x;
    const int Y0 = positions[2 * n];
    const int X0 = positions[2 * n + 1];

    if (t < 128) {
        int p_ = t >> 3, c_ = t & 7;
        float angA = -2.0f * 3.14159265358979323846f
                     * (float)(c_ * BR4(p_)) / 128.0f;
        float s, cc; __sincosf(angA, &s, &cc);
        tA[t] = (v2f){cc, s};
        float angB = -2.0f * 3.14159265358979323846f
                     * (float)(p_ * BR3(c_)) / 128.0f;
        __sincosf(angB, &s, &cc);
        tB[t] = (v2f){cc, s};
        int kh = BR3(c_) + 8 * BR4(p_);
        float fy = (float)(kh < 64 ? kh : kh - 128) * (1.0f / 25.6f);
        float ph = -0.15707963267948966f * fy * fy;
        float ps, pcs; __sincosf(ph, &ps, &pcs);
        pytp[t] = (v2f){pcs * (1.0f / 16384.0f), ps * (1.0f / 16384.0f)};
    }

    // per-thread constants for the cross-8 stages
    const float sA = (c < 4) ? 1.0f : -1.0f;
    const float sB = (c & 2) ? -1.0f : 1.0f;
    const float sC = (c & 1) ? -1.0f : 1.0f;
    const v2f sAp = {sA, sA}, sBp = {sB, sB}, sCp = {sC, sC};
    const v2f fA  = {FA_RE[c], FA_IM[c]};
    const v2f rrf = ((c & 3) == 3) ? (v2f){0.0f, -1.0f} : (v2f){1.0f, 0.0f};

    const v2f W[8] = {
        { 1.0f,         0.0f        },
        { 0.923879533f, 0.382683432f},
        { 0.707106781f, 0.707106781f},
        { 0.382683432f, 0.923879533f},
        { 0.0f,         1.0f        },
        {-0.382683432f, 0.923879533f},
        {-0.707106781f, 0.707106781f},
        {-0.923879533f, 0.382683432f},
    };

    // propagator x-factors for each of this thread's kw rows
    float fxa = (float)(ga < 64 ? ga : ga - 128) * (1.0f / 25.6f);
    float pha = -0.15707963267948966f * fxa * fxa;
    float pxs, pxc; __sincosf(pha, &pxs, &pxc);
    const v2f px_a = {pxc, pxs};
    float fxb = (float)(gb < 64 ? gb : gb - 128) * (1.0f / 25.6f);
    float phb = -0.15707963267948966f * fxb * fxb;
    __sincosf(phb, &pxs, &pxc);
    const v2f px_b = {pxc, pxs};
    __syncthreads();

    const long long base = (long long)n * NPIX;
    // transpose address bases, per row
    const int a1w_a = rho_a ^ rc;
    const int a1w_b = rho_b ^ rc;
    const int a1r_a = ga * LSTR + (c ^ gha);
    const int a1r_b = gb * LSTR + (c ^ ghb);
    const int a2w_a = rho_a ^ c;
    const int a2w_b = rho_b ^ c;
    const int a2r_a = ga * LSTR + (rc ^ gha);
    const int a2r_b = gb * LSTR + (rc ^ ghb);

    v2f va[16], vb[16];

    for (int m = 0; m < NMODES; m++) {
        __syncthreads();   // protect LTH reuse across modes
        #pragma unroll
        for (int i = 0; i < 16; i++) {           // ex = probe[m]*patch(slice0)
            int w  = c + 8 * i;
            int pia = m * NPIX + ga * 128 + w;
            v2f pra = {probe_re[pia], probe_im[pia]};
            int oia = (Y0 + ga) * OBJW + X0 + w;
            v2f oba = {obj_re[oia], obj_im[oia]};
            va[i] = pk_cmul(pra, oba);
            int pib = m * NPIX + gb * 128 + w;
            v2f prb = {probe_re[pib], probe_im[pib]};
            int oib = (Y0 + gb) * OBJW + X0 + w;
            v2f obb = {obj_re[oib], obj_im[oib]};
            vb[i] = pk_cmul(prb, obb);
        }

        for (int s = 1; s < NSLICES; s++) {
            pass_A_fwd(va, c, sAp, sBp, sCp, fA, rrf, W, tA);
            pass_A_fwd(vb, c, sAp, sBp, sCp, fA, rrf, W, tA);
            #pragma unroll                       // T1 write [kw][r]
            for (int p = 0; p < 16; p++) {
                int kw = BR4(p) + 16 * rc;
                LTH[kw * LSTR + a1w_a] = toh2(va[p]);
                LTH[kw * LSTR + a1w_b] = toh2(vb[p]);
            }
            __syncthreads();
            #pragma unroll                       // T1 read: major kw = ga / gb
            for (int i = 0; i < 16; i++) {
                va[i] = frh2(LTH[a1r_a + 8 * i]);
                vb[i] = frh2(LTH[a1r_b + 8 * i]);
            }
            __syncthreads();
            pass_B_fwd(va, c, sAp, sBp, sCp, fA, rrf, W, tB);
            pass_B_fwd(vb, c, sAp, sBp, sCp, fA, rrf, W, tB);
            #pragma unroll                       // * prop
            for (int p = 0; p < 16; p++) {
                v2f py = pytp[8 * p + c];
                va[p] = pk_cmul(va[p], pk_cmul(py, px_a));
                vb[p] = pk_cmul(vb[p], pk_cmul(py, px_b));
            }
            pass_B_inv(va, c, sAp, sBp, sCp, fA, rrf, W, tB);
            pass_B_inv(vb, c, sAp, sBp, sCp, fA, rrf, W, tB);
            #pragma unroll                       // T2 write [r=i+16c][kw]
            for (int i = 0; i < 16; i++) {
                LTH[(i + 16 * c) * LSTR + a2w_a] = toh2(va[i]);
                LTH[(i + 16 * c) * LSTR + a2w_b] = toh2(vb[i]);
            }
            __syncthreads();
            #pragma unroll                       // T2 read -> rows ga / gb
            for (int p = 0; p < 16; p++) {
                va[p] = frh2(LTH[a2r_a + 8 * BR4(p)]);
                vb[p] = frh2(LTH[a2r_b + 8 * BR4(p)]);
            }
            __syncthreads();
            pass_A_inv(va, c, sAp, sBp, sCp, fA, rrf, W, tA);
            pass_A_inv(vb, c, sAp, sBp, sCp, fA, rrf, W, tA);
            #pragma unroll                       // * patch(slice s)
            for (int i = 0; i < 16; i++) {
                int w  = c + 8 * i;
                int oia = (s * OBJW + Y0 + ga) * OBJW + X0 + w;
                v2f oba = {obj_re[oia], obj_im[oia]};
                va[i] = pk_cmul(va[i], oba);
                int oib = (s * OBJW + Y0 + gb) * OBJW + X0 + w;
                v2f obb = {obj_re[oib], obj_im[oib]};
                vb[i] = pk_cmul(vb[i], obb);
            }
        }

        // final FFT2: Fw, T1, Fh(pass_B), |.|^2 RMW into out
        pass_A_fwd(va, c, sAp, sBp, sCp, fA, rrf, W, tA);
        pass_A_fwd(vb, c, sAp, sBp, sCp, fA, rrf, W, tA);
        #pragma unroll
        for (int p = 0; p < 16; p++) {
            int kw = BR4(p) + 16 * rc;
            LTH[kw * LSTR + a1w_a] = toh2(va[p]);
            LTH[kw * LSTR + a1w_b] = toh2(vb[p]);
        }
        __syncthreads();
        #pragma unroll
        for (int i = 0; i < 16; i++) {
            va[i] = frh2(LTH[a1r_a + 8 * i]);
            vb[i] = frh2(LTH[a1r_b + 8 * i]);
        }
        pass_B_fwd(va, c, sAp, sBp, sCp, fA, rrf, W, tB);
        pass_B_fwd(vb, c, sAp, sBp, sCp, fA, rrf, W, tB);
        // fftshift: (kh,kw)->(kh^64,kw^64); kh=br3(c)+8BR4(p), kw=ga/gb.
        #pragma unroll
        for (int p = 0; p < 16; p++) {
            int kh = BR3(c) + 8 * BR4(p);
            long long oia = base + (long long)(((kh ^ 64) << 7) + (ga ^ 64));
            float vala = fmaf(va[p].x, va[p].x, va[p].y * va[p].y);
            if (m > 0) vala += out[oia];
            out[oia] = vala;
            long long oib = base + (long long)(((kh ^ 64) << 7) + (gb ^ 64));
            float valb = fmaf(vb[p].x, vb[p].x, vb[p].y * vb[p].y);
            if (m > 0) valb += out[oib];
            out[oib] = valb;
        }
    }
}

extern "C" void kernel_launch(void* const* d_in, const int* in_sizes, int n_in,
                              void* d_out, int out_size, void* d_ws, size_t ws_size,
                              hipStream_t stream) {
    const float* probe_re = (const float*)d_in[0];
    const float* probe_im = (const float*)d_in[1];
    const float* obj_re   = (const float*)d_in[2];
    const float* obj_im   = (const float*)d_in[3];
    const int*   pos      = (const int*)d_in[4];
    float* out = (float*)d_out;

    const int N = out_size / NPIX;   // 512 positions
    multislice_kernel<<<dim3(N), dim3(NT), 0, stream>>>(
        probe_re, probe_im, obj_re, obj_im, pos, out);
}

// Round 4
// 1548.663 us; speedup vs baseline: 1.0024x; 1.0024x over previous
//
#include <hip/hip_runtime.h>
#include <hip/hip_fp16.h>
#include <math.h>

#define NT      512
#define NPIX    16384
#define NSLICES 8
#define NMODES  4
#define OBJW    512
#define LSTR    136        // padded major stride (half2 units): 136%32=8

typedef float v2f __attribute__((ext_vector_type(2)));

// ---- packed fp32 complex primitives (VOP3P) --------------------------------
__device__ __forceinline__ v2f pk_add(v2f a, v2f b) {
    v2f d; asm("v_pk_add_f32 %0, %1, %2" : "=v"(d) : "v"(a), "v"(b)); return d;
}
__device__ __forceinline__ v2f pk_sub(v2f a, v2f b) {
    v2f d; asm("v_pk_add_f32 %0, %1, %2 neg_lo:[0,1] neg_hi:[0,1]"
               : "=v"(d) : "v"(a), "v"(b)); return d;
}
__device__ __forceinline__ v2f pk_fma(v2f a, v2f b, v2f c) {
    v2f d; asm("v_pk_fma_f32 %0, %1, %2, %3" : "=v"(d) : "v"(a), "v"(b), "v"(c)); return d;
}
// d = a*b (complex):  t=(ax*bx, ay*bx);  d=(t.x - ay*by, t.y + ax*by)
__device__ __forceinline__ v2f pk_cmul(v2f a, v2f b) {
    v2f t, d;
    asm("v_pk_mul_f32 %0, %1, %2 op_sel:[0,0] op_sel_hi:[1,0]"
        : "=v"(t) : "v"(a), "v"(b));
    asm("v_pk_fma_f32 %0, %1, %2, %3 op_sel:[1,1,0] op_sel_hi:[0,1,1] neg_lo:[1,0,0]"
        : "=v"(d) : "v"(a), "v"(b), "v"(t));
    return d;
}
// d = a*conj(b)
__device__ __forceinline__ v2f pk_cmulc(v2f a, v2f b) {
    v2f t, d;
    asm("v_pk_mul_f32 %0, %1, %2 op_sel:[0,0] op_sel_hi:[1,0]"
        : "=v"(t) : "v"(a), "v"(b));
    asm("v_pk_fma_f32 %0, %1, %2, %3 op_sel:[1,1,0] op_sel_hi:[0,1,1] neg_hi:[1,0,0]"
        : "=v"(d) : "v"(a), "v"(b), "v"(t));
    return d;
}
__device__ __forceinline__ v2f pk_mnegi(v2f a) { return (v2f){a.y, -a.x}; }  // a * -i
__device__ __forceinline__ v2f pk_mposi(v2f a) { return (v2f){-a.y, a.x}; }  // a * +i

// 4-bit reversal (constexpr -> folds to literals in unrolled loops)
__host__ __device__ constexpr int BR4(int p) {
    return ((p & 1) << 3) | ((p & 2) << 1) | ((p & 4) >> 1) | ((p & 8) >> 3);
}
__host__ __device__ constexpr int BR3(int c) {
    return ((c & 1) << 2) | (c & 2) | ((c & 4) >> 2);
}

// ---- lane exchange primitives ---------------------------------------------
__device__ __forceinline__ float xor1f(float x) {
    int i = __float_as_int(x);
    return __int_as_float(__builtin_amdgcn_update_dpp(i, i, 0xB1, 0xF, 0xF, false));
}
__device__ __forceinline__ float xor2f(float x) {
    int i = __float_as_int(x);
    return __int_as_float(__builtin_amdgcn_update_dpp(i, i, 0x4E, 0xF, 0xF, false));
}
__device__ __forceinline__ float xor4f(float x) {
    return __int_as_float(__builtin_amdgcn_ds_swizzle(__float_as_int(x), 0x101F));
}

// cross-8 stage-A twiddle fA(c) = (c<4) ? 1 : W8^(c-4)
__device__ __constant__ float FA_RE[8] = {1,1,1,1, 1.0f,  0.707106781f,  0.0f, -0.707106781f};
__device__ __constant__ float FA_IM[8] = {0,0,0,0, 0.0f, -0.707106781f, -1.0f, -0.707106781f};

// ---- local 16-point FFT in registers (packed) ------------------------------
__device__ __forceinline__ void fft16_fwd(v2f v[16], const v2f* W) {
    #pragma unroll
    for (int s = 8; s >= 1; s >>= 1) {
        #pragma unroll
        for (int q = 0; q < 16; q += 2 * s) {
            #pragma unroll
            for (int j = 0; j < s; j++) {
                const int tw = j * (8 / s);
                v2f u = v[q + j], w = v[q + j + s];
                v[q + j] = pk_add(u, w);
                v2f d = pk_sub(u, w);
                v[q + j + s] = (tw == 0) ? d
                             : (tw == 4) ? pk_mnegi(d)
                                         : pk_cmulc(d, W[tw]);
            }
        }
    }
}
__device__ __forceinline__ void fft16_inv(v2f v[16], const v2f* W) {
    #pragma unroll
    for (int s = 1; s <= 8; s <<= 1) {
        #pragma unroll
        for (int q = 0; q < 16; q += 2 * s) {
            #pragma unroll
            for (int j = 0; j < s; j++) {
                const int tw = j * (8 / s);
                v2f u = v[q + j], w = v[q + j + s];
                v2f tv = (tw == 0) ? w
                       : (tw == 4) ? pk_mposi(w)
                                   : pk_cmul(w, W[tw]);
                v[q + j]     = pk_add(u, tv);
                v[q + j + s] = pk_sub(u, tv);
            }
        }
    }
}

// ---- cross-thread DFT8 over sub-index c (xor 4,2,1) ------------------------
__device__ __forceinline__ void cross8_fwd(v2f v[16], v2f sAp, v2f sBp, v2f sCp,
                                           v2f fA, v2f rrf) {
    #pragma unroll
    for (int p = 0; p < 16; p++) {
        v2f o;
        o.x = xor4f(v[p].x); o.y = xor4f(v[p].y);
        v2f a = pk_fma(sAp, v[p], o);
        v2f b = pk_cmul(a, fA);
        o.x = xor2f(b.x); o.y = xor2f(b.y);
        v2f n = pk_fma(sBp, b, o);
        v2f r = pk_cmul(n, rrf);
        o.x = xor1f(r.x); o.y = xor1f(r.y);
        v[p] = pk_fma(sCp, r, o);
    }
}
__device__ __forceinline__ void cross8_inv(v2f v[16], v2f sAp, v2f sBp, v2f sCp,
                                           v2f fA, v2f rrf) {
    #pragma unroll
    for (int p = 0; p < 16; p++) {
        v2f o;
        o.x = xor1f(v[p].x); o.y = xor1f(v[p].y);
        v2f n = pk_fma(sCp, v[p], o);
        v2f r = pk_cmulc(n, rrf);
        o.x = xor2f(r.x); o.y = xor2f(r.y);
        v2f b = pk_fma(sBp, r, o);
        v2f a = pk_cmulc(b, fA);
        o.x = xor4f(a.x); o.y = xor4f(a.y);
        v[p] = pk_fma(sAp, a, o);
    }
}

// ---- pass A (local-first): input reg i = elem c+8i; out reg p = BR4(p)+16rc
__device__ __forceinline__ void pass_A_fwd(v2f v[16], int c, v2f sAp, v2f sBp,
                                           v2f sCp, v2f fA, v2f rrf,
                                           const v2f* W, const v2f* tA) {
    fft16_fwd(v, W);
    #pragma unroll
    for (int p = 0; p < 16; p++) v[p] = pk_cmul(v[p], tA[8 * p + c]);
    cross8_fwd(v, sAp, sBp, sCp, fA, rrf);
}
__device__ __forceinline__ void pass_A_inv(v2f v[16], int c, v2f sAp, v2f sBp,
                                           v2f sCp, v2f fA, v2f rrf,
                                           const v2f* W, const v2f* tA) {
    cross8_inv(v, sAp, sBp, sCp, fA, rrf);
    #pragma unroll
    for (int p = 0; p < 16; p++) v[p] = pk_cmulc(v[p], tA[8 * p + c]);
    fft16_inv(v, W);
}

// ---- pass B (cross-first): input reg i = elem i+16c
__device__ __forceinline__ void pass_B_fwd(v2f v[16], int c, v2f sAp, v2f sBp,
                                           v2f sCp, v2f fA, v2f rrf,
                                           const v2f* W, const v2f* tB) {
    cross8_fwd(v, sAp, sBp, sCp, fA, rrf);
    #pragma unroll
    for (int i = 0; i < 16; i++) v[i] = pk_cmul(v[i], tB[8 * i + c]);
    fft16_fwd(v, W);
}
__device__ __forceinline__ void pass_B_inv(v2f v[16], int c, v2f sAp, v2f sBp,
                                           v2f sCp, v2f fA, v2f rrf,
                                           const v2f* W, const v2f* tB) {
    fft16_inv(v, W);
    #pragma unroll
    for (int i = 0; i < 16; i++) v[i] = pk_cmulc(v[i], tB[8 * i + c]);
    cross8_inv(v, sAp, sBp, sCp, fA, rrf);
}

// ---- conversions -----------------------------------------------------------
__device__ __forceinline__ __half2 toh2(v2f a) {
    return __float22half2_rn(make_float2(a.x, a.y));
}
__device__ __forceinline__ v2f frh2(__half2 h) {
    float2 f = __half22float2(h);
    return (v2f){f.x, f.y};
}

// ---- main kernel: 512 threads, 2 rows/thread (g0 and g0+64) ----------------
// 2 WGs/CU (2x72.7KB LDS = 145KB): two independent barrier domains per CU.
// amdgpu_waves_per_eu(4,4) pins the register budget at exactly 128 VGPR
// (4 waves x 128 = 512-reg file) -- round 3's __launch_bounds__(512,4)
// produced a 64-VGPR budget and catastrophic scratch spill (2.6GB writes).
__global__ void
__attribute__((amdgpu_flat_work_group_size(512, 512), amdgpu_waves_per_eu(4, 4)))
multislice_kernel(const float* __restrict__ probe_re,
                  const float* __restrict__ probe_im,
                  const float* __restrict__ obj_re,
                  const float* __restrict__ obj_im,
                  const int*   __restrict__ positions,
                  float*       __restrict__ out)
{
    __shared__ __half2 LTH[128 * LSTR];   // 69632 B transpose buffer (fp16)
    __shared__ v2f     tA[128];           // pass-A twiddle [8p+c]
    __shared__ v2f     tB[128];           // pass-B twiddle [8i+c]
    __shared__ v2f     pytp[128];         // prop y-factor/16384, kh=br3(c)+8BR4(p)

    const int t  = threadIdx.x;
    const int g0 = t >> 3;                      // 0..63
    const int c  = t & 7;
    const int rc = BR3(c);
    const int ga = g0, gb = g0 + 64;            // this thread's two rows
    const int gha = ga >> 4, ghb = gb >> 4;
    const int rho_a = ((ga & 15) << 3) | gha;
    const int rho_b = ((gb & 15) << 3) | ghb;
    const int n  = blockIdx.x;
    const int Y0 = positions[2 * n];
    const int X0 = positions[2 * n + 1];

    if (t < 128) {
        int p_ = t >> 3, c_ = t & 7;
        float angA = -2.0f * 3.14159265358979323846f
                     * (float)(c_ * BR4(p_)) / 128.0f;
        float s, cc; __sincosf(angA, &s, &cc);
        tA[t] = (v2f){cc, s};
        float angB = -2.0f * 3.14159265358979323846f
                     * (float)(p_ * BR3(c_)) / 128.0f;
        __sincosf(angB, &s, &cc);
        tB[t] = (v2f){cc, s};
        int kh = BR3(c_) + 8 * BR4(p_);
        float fy = (float)(kh < 64 ? kh : kh - 128) * (1.0f / 25.6f);
        float ph = -0.15707963267948966f * fy * fy;
        float ps, pcs; __sincosf(ph, &ps, &pcs);
        pytp[t] = (v2f){pcs * (1.0f / 16384.0f), ps * (1.0f / 16384.0f)};
    }

    // per-thread constants for the cross-8 stages
    const float sA = (c < 4) ? 1.0f : -1.0f;
    const float sB = (c & 2) ? -1.0f : 1.0f;
    const float sC = (c & 1) ? -1.0f : 1.0f;
    const v2f sAp = {sA, sA}, sBp = {sB, sB}, sCp = {sC, sC};
    const v2f fA  = {FA_RE[c], FA_IM[c]};
    const v2f rrf = ((c & 3) == 3) ? (v2f){0.0f, -1.0f} : (v2f){1.0f, 0.0f};

    const v2f W[8] = {
        { 1.0f,         0.0f        },
        { 0.923879533f, 0.382683432f},
        { 0.707106781f, 0.707106781f},
        { 0.382683432f, 0.923879533f},
        { 0.0f,         1.0f        },
        {-0.382683432f, 0.923879533f},
        {-0.707106781f, 0.707106781f},
        {-0.923879533f, 0.382683432f},
    };

    // propagator x-factors for each of this thread's kw rows
    float fxa = (float)(ga < 64 ? ga : ga - 128) * (1.0f / 25.6f);
    float pha = -0.15707963267948966f * fxa * fxa;
    float pxs, pxc; __sincosf(pha, &pxs, &pxc);
    const v2f px_a = {pxc, pxs};
    float fxb = (float)(gb < 64 ? gb : gb - 128) * (1.0f / 25.6f);
    float phb = -0.15707963267948966f * fxb * fxb;
    __sincosf(phb, &pxs, &pxc);
    const v2f px_b = {pxc, pxs};
    __syncthreads();

    const long long base = (long long)n * NPIX;
    // transpose address bases, per row
    const int a1w_a = rho_a ^ rc;
    const int a1w_b = rho_b ^ rc;
    const int a1r_a = ga * LSTR + (c ^ gha);
    const int a1r_b = gb * LSTR + (c ^ ghb);
    const int a2w_a = rho_a ^ c;
    const int a2w_b = rho_b ^ c;
    const int a2r_a = ga * LSTR + (rc ^ gha);
    const int a2r_b = gb * LSTR + (rc ^ ghb);

    v2f va[16], vb[16];

    for (int m = 0; m < NMODES; m++) {
        __syncthreads();   // protect LTH reuse across modes
        #pragma unroll
        for (int i = 0; i < 16; i++) {           // ex = probe[m]*patch(slice0)
            int w  = c + 8 * i;
            int pia = m * NPIX + ga * 128 + w;
            v2f pra = {probe_re[pia], probe_im[pia]};
            int oia = (Y0 + ga) * OBJW + X0 + w;
            v2f oba = {obj_re[oia], obj_im[oia]};
            va[i] = pk_cmul(pra, oba);
            int pib = m * NPIX + gb * 128 + w;
            v2f prb = {probe_re[pib], probe_im[pib]};
            int oib = (Y0 + gb) * OBJW + X0 + w;
            v2f obb = {obj_re[oib], obj_im[oib]};
            vb[i] = pk_cmul(prb, obb);
        }

        for (int s = 1; s < NSLICES; s++) {
            pass_A_fwd(va, c, sAp, sBp, sCp, fA, rrf, W, tA);
            pass_A_fwd(vb, c, sAp, sBp, sCp, fA, rrf, W, tA);
            #pragma unroll                       // T1 write [kw][r]
            for (int p = 0; p < 16; p++) {
                int kw = BR4(p) + 16 * rc;
                LTH[kw * LSTR + a1w_a] = toh2(va[p]);
                LTH[kw * LSTR + a1w_b] = toh2(vb[p]);
            }
            __syncthreads();
            #pragma unroll                       // T1 read: major kw = ga / gb
            for (int i = 0; i < 16; i++) {
                va[i] = frh2(LTH[a1r_a + 8 * i]);
                vb[i] = frh2(LTH[a1r_b + 8 * i]);
            }
            __syncthreads();
            pass_B_fwd(va, c, sAp, sBp, sCp, fA, rrf, W, tB);
            pass_B_fwd(vb, c, sAp, sBp, sCp, fA, rrf, W, tB);
            #pragma unroll                       // * prop
            for (int p = 0; p < 16; p++) {
                v2f py = pytp[8 * p + c];
                va[p] = pk_cmul(va[p], pk_cmul(py, px_a));
                vb[p] = pk_cmul(vb[p], pk_cmul(py, px_b));
            }
            pass_B_inv(va, c, sAp, sBp, sCp, fA, rrf, W, tB);
            pass_B_inv(vb, c, sAp, sBp, sCp, fA, rrf, W, tB);
            #pragma unroll                       // T2 write [r=i+16c][kw]
            for (int i = 0; i < 16; i++) {
                LTH[(i + 16 * c) * LSTR + a2w_a] = toh2(va[i]);
                LTH[(i + 16 * c) * LSTR + a2w_b] = toh2(vb[i]);
            }
            __syncthreads();
            #pragma unroll                       // T2 read -> rows ga / gb
            for (int p = 0; p < 16; p++) {
                va[p] = frh2(LTH[a2r_a + 8 * BR4(p)]);
                vb[p] = frh2(LTH[a2r_b + 8 * BR4(p)]);
            }
            __syncthreads();
            pass_A_inv(va, c, sAp, sBp, sCp, fA, rrf, W, tA);
            pass_A_inv(vb, c, sAp, sBp, sCp, fA, rrf, W, tA);
            #pragma unroll                       // * patch(slice s)
            for (int i = 0; i < 16; i++) {
                int w  = c + 8 * i;
                int oia = (s * OBJW + Y0 + ga) * OBJW + X0 + w;
                v2f oba = {obj_re[oia], obj_im[oia]};
                va[i] = pk_cmul(va[i], oba);
                int oib = (s * OBJW + Y0 + gb) * OBJW + X0 + w;
                v2f obb = {obj_re[oib], obj_im[oib]};
                vb[i] = pk_cmul(vb[i], obb);
            }
        }

        // final FFT2: Fw, T1, Fh(pass_B), |.|^2 RMW into out
        pass_A_fwd(va, c, sAp, sBp, sCp, fA, rrf, W, tA);
        pass_A_fwd(vb, c, sAp, sBp, sCp, fA, rrf, W, tA);
        #pragma unroll
        for (int p = 0; p < 16; p++) {
            int kw = BR4(p) + 16 * rc;
            LTH[kw * LSTR + a1w_a] = toh2(va[p]);
            LTH[kw * LSTR + a1w_b] = toh2(vb[p]);
        }
        __syncthreads();
        #pragma unroll
        for (int i = 0; i < 16; i++) {
            va[i] = frh2(LTH[a1r_a + 8 * i]);
            vb[i] = frh2(LTH[a1r_b + 8 * i]);
        }
        pass_B_fwd(va, c, sAp, sBp, sCp, fA, rrf, W, tB);
        pass_B_fwd(vb, c, sAp, sBp, sCp, fA, rrf, W, tB);
        // fftshift: (kh,kw)->(kh^64,kw^64); kh=br3(c)+8BR4(p), kw=ga/gb.
        #pragma unroll
        for (int p = 0; p < 16; p++) {
            int kh = BR3(c) + 8 * BR4(p);
            long long oia = base + (long long)(((kh ^ 64) << 7) + (ga ^ 64));
            float vala = fmaf(va[p].x, va[p].x, va[p].y * va[p].y);
            if (m > 0) vala += out[oia];
            out[oia] = vala;
            long long oib = base + (long long)(((kh ^ 64) << 7) + (gb ^ 64));
            float valb = fmaf(vb[p].x, vb[p].x, vb[p].y * vb[p].y);
            if (m > 0) valb += out[oib];
            out[oib] = valb;
        }
    }
}

extern "C" void kernel_launch(void* const* d_in, const int* in_sizes, int n_in,
                              void* d_out, int out_size, void* d_ws, size_t ws_size,
                              hipStream_t stream) {
    const float* probe_re = (const float*)d_in[0];
    const float* probe_im = (const float*)d_in[1];
    const float* obj_re   = (const float*)d_in[2];
    const float* obj_im   = (const float*)d_in[3];
    const int*   pos      = (const int*)d_in[4];
    float* out = (float*)d_out;

    const int N = out_size / NPIX;   // 512 positions
    multislice_kernel<<<dim3(N), dim3(NT), 0, stream>>>(
        probe_re, probe_im, obj_re, obj_im, pos, out);
}